// Round 6
// baseline (1365.721 us; speedup 1.0000x reference)
//
#include <hip/hip_runtime.h>
#include <math.h>

// DigitCaps routing constants
#define B_SZ 64
#define P_SZ 2048
#define PD   16
#define N_SZ 32
#define D_SZ 32
#define ND   1024            // N_SZ * D_SZ
#define PC   8               // p per fused block (r6: 16->8)
#define BC   8               // b per fused block
#define NPC  (P_SZ / PC)     // 256
#define NBC  (B_SZ / BC)     // 8  -> grid 2048 blocks = 8 blocks/CU

typedef _Float16 half2_t __attribute__((ext_vector_type(2)));

__device__ __forceinline__ float dot2acc(unsigned a, unsigned b, float acc) {
#if __has_builtin(__builtin_amdgcn_fdot2)
    return __builtin_amdgcn_fdot2(__builtin_bit_cast(half2_t, a),
                                  __builtin_bit_cast(half2_t, b), acc, false);
#else
    const half2_t ha = __builtin_bit_cast(half2_t, a);
    const half2_t hb = __builtin_bit_cast(half2_t, b);
    return acc + (float)ha[0] * (float)hb[0] + (float)ha[1] * (float)hb[1];
#endif
}

__device__ __forceinline__ unsigned packh2(float a, float b) {
    half2_t h; h[0] = (_Float16)a; h[1] = (_Float16)b;
    return __builtin_bit_cast(unsigned, h);
}

__device__ __forceinline__ float4 unpackh4(uint2 u) {
    const half2_t lo = __builtin_bit_cast(half2_t, u.x);
    const half2_t hi = __builtin_bit_cast(half2_t, u.y);
    return make_float4((float)lo[0], (float)lo[1], (float)hi[0], (float)hi[1]);
}

__device__ __forceinline__ float dot4(const float4 a, const float4 b) {
    return a.x * b.x + a.y * b.y + a.z * b.z + a.w * b.w;
}

// w (P,ND,PD) fp32 -> w2 f16, chunked so fused thread t reads coalesced:
// uint4 W[k] at w2u4[(p*8+k)*256 + t] holds w[p][4t + (k>>1)][(k&1)*8 .. +7]
__global__ __launch_bounds__(256) void repack_w(const float4* __restrict__ w4,
                                                unsigned* __restrict__ w2) {
    const size_t g = (size_t)blockIdx.x * 256 + threadIdx.x;  // < 8388608
    const float4 f4 = w4[g];
    const size_t f = g * 4;
    const int p  = (int)(f >> 14);
    const int nd = (int)((f >> 4) & 1023);
    const int q0 = (int)(f & 15);
    const int t  = nd >> 2, r = nd & 3;
    const int k  = r * 2 + (q0 >> 3);
    const int jp = (q0 & 7) >> 1;
    const size_t du = (((size_t)p * 8 + k) * 256 + t) * 4 + jp;
    uint2 val = { packh2(f4.x, f4.y), packh2(f4.z, f4.w) };
    *(uint2*)(w2 + du) = val;
}

// x (B,P,PD) fp32 -> x2 f16 pairs: x2u4[(b*P+p)*2 + half]
__global__ __launch_bounds__(256) void repack_x(const float4* __restrict__ x4,
                                                uint4* __restrict__ x2) {
    const size_t g = (size_t)blockIdx.x * 256 + threadIdx.x;  // < 262144
    const float4 a = x4[g * 2], b = x4[g * 2 + 1];
    uint4 o;
    o.x = packh2(a.x, a.y); o.y = packh2(a.z, a.w);
    o.z = packh2(b.x, b.y); o.w = packh2(b.z, b.w);
    x2[g] = o;
}

__device__ __forceinline__ float4 predict(const uint4 (&W)[8], const unsigned* X) {
    float s; float4 pr;
    s = dot2acc(W[0].x, X[0], 0.f); s = dot2acc(W[0].y, X[1], s);
    s = dot2acc(W[0].z, X[2], s);   s = dot2acc(W[0].w, X[3], s);
    s = dot2acc(W[1].x, X[4], s);   s = dot2acc(W[1].y, X[5], s);
    s = dot2acc(W[1].z, X[6], s);   s = dot2acc(W[1].w, X[7], s);
    pr.x = s;
    s = dot2acc(W[2].x, X[0], 0.f); s = dot2acc(W[2].y, X[1], s);
    s = dot2acc(W[2].z, X[2], s);   s = dot2acc(W[2].w, X[3], s);
    s = dot2acc(W[3].x, X[4], s);   s = dot2acc(W[3].y, X[5], s);
    s = dot2acc(W[3].z, X[6], s);   s = dot2acc(W[3].w, X[7], s);
    pr.y = s;
    s = dot2acc(W[4].x, X[0], 0.f); s = dot2acc(W[4].y, X[1], s);
    s = dot2acc(W[4].z, X[2], s);   s = dot2acc(W[4].w, X[3], s);
    s = dot2acc(W[5].x, X[4], s);   s = dot2acc(W[5].y, X[5], s);
    s = dot2acc(W[5].z, X[6], s);   s = dot2acc(W[5].w, X[7], s);
    pr.z = s;
    s = dot2acc(W[6].x, X[0], 0.f); s = dot2acc(W[6].y, X[1], s);
    s = dot2acc(W[6].z, X[2], s);   s = dot2acc(W[6].w, X[3], s);
    s = dot2acc(W[7].x, X[4], s);   s = dot2acc(W[7].y, X[5], s);
    s = dot2acc(W[7].z, X[6], s);   s = dot2acc(W[7].w, X[7], s);
    pr.w = s;
    return pr;
}

// One routing step. Thread t owns nd = 4t..4t+3 (n = t>>3).
// MODE==0: c=1/32; MODE==1: b=agr; MODE==2: b+=agr; c=softmax_n(b)
// r6: PC=8, grid 2048 blocks; v in LDS as f16 (16.6 KiB LDS total);
// VGPR=64 (proven by r5 binary) -> 8 blocks/CU, 32 waves/CU.
template <int MODE>
__global__ __launch_bounds__(256, 8) void fused_pass(
    const uint4* __restrict__ x2, const uint4* __restrict__ w2,
    const float* __restrict__ v_in, float* __restrict__ b_io,
    uint2* __restrict__ s_part)
{
    const int t     = threadIdx.x;
    const int pc    = blockIdx.x;
    const int pcswz = (pc & 7) * (NPC / 8) + (pc >> 3);
    const int bc    = blockIdx.y;          // 0..NBC-1
    const int p0    = pcswz * PC, b0 = bc * BC;
    const int n     = t >> 3;
    const int wv    = t >> 6;
    const int lane  = t & 63;

    __shared__ uint2 vs2[BC * 256];        // v as f16 pairs, 16 KiB
    __shared__ float sden[2][16];          // [epoch parity][j*4 + wave]

    if (MODE != 0) {
        const float4* vg = (const float4*)v_in;
        #pragma unroll
        for (int i = 0; i < BC; ++i) {
            const int idx = t + 256 * i;   // 0..2047
            const float4 vv = vg[(size_t)(b0 + (idx >> 8)) * 256 + (idx & 255)];
            uint2 u = { packh2(vv.x, vv.y), packh2(vv.z, vv.w) };
            vs2[idx] = u;
        }
        __syncthreads();
    }

    float4 sacc[BC];
    #pragma unroll
    for (int i = 0; i < BC; ++i) sacc[i] = make_float4(0.f, 0.f, 0.f, 0.f);

    const uint4* wbase = w2 + (size_t)p0 * (8 * 256) + t;
    const uint4* xbase = x2 + (size_t)b0 * P_SZ * 2;

    for (int pl = 0; pl < PC; ++pl) {
        const int p = p0 + pl;
        uint4 W[8];
        #pragma unroll
        for (int k = 0; k < 8; ++k) W[k] = wbase[(size_t)pl * 2048 + k * 256];

        if (MODE == 0) {
            #pragma unroll
            for (int j = 0; j < BC; ++j) {
                const uint4* xp = xbase + ((size_t)j * P_SZ + p) * 2;
                const uint4 xa = xp[0], xb = xp[1];
                const unsigned X[8] = {xa.x, xa.y, xa.z, xa.w, xb.x, xb.y, xb.z, xb.w};
                const float4 pr = predict(W, X);
                sacc[j].x += pr.x * (1.0f / 32.0f);
                sacc[j].y += pr.y * (1.0f / 32.0f);
                sacc[j].z += pr.z * (1.0f / 32.0f);
                sacc[j].w += pr.w * (1.0f / 32.0f);
            }
        } else {
            #pragma unroll
            for (int h = 0; h < 2; ++h) {
                const int par = h;
                float4 pr[4];
                float  ap[4], ee[4], bold[4];
                if (MODE == 2) {
                    #pragma unroll
                    for (int j = 0; j < 4; ++j)
                        bold[j] = b_io[((size_t)(b0 + h * 4 + j) * P_SZ + p) * N_SZ + n];
                }
                #pragma unroll
                for (int j = 0; j < 4; ++j) {
                    const int bl = h * 4 + j;
                    const uint4* xp = xbase + ((size_t)bl * P_SZ + p) * 2;
                    const uint4 xa = xp[0], xb = xp[1];
                    const unsigned X[8] = {xa.x, xa.y, xa.z, xa.w, xb.x, xb.y, xb.z, xb.w};
                    pr[j] = predict(W, X);
                    ap[j] = dot4(pr[j], unpackh4(vs2[bl * 256 + t]));
                }
                #pragma unroll
                for (int j = 0; j < 4; ++j) {
                    ap[j] += __shfl_xor(ap[j], 1);
                    ap[j] += __shfl_xor(ap[j], 2);
                    ap[j] += __shfl_xor(ap[j], 4);
                }
                #pragma unroll
                for (int j = 0; j < 4; ++j) {
                    const size_t bidx = ((size_t)(b0 + h * 4 + j) * P_SZ + p) * N_SZ + n;
                    const float bnew = (MODE == 1) ? ap[j] : (bold[j] + ap[j]);
                    if ((t & 7) == 0) b_io[bidx] = bnew;
                    ee[j] = __expf(bnew);
                }
                #pragma unroll
                for (int j = 0; j < 4; ++j) {
                    float ps = ee[j];
                    ps += __shfl_xor(ps, 8);
                    ps += __shfl_xor(ps, 16);
                    ps += __shfl_xor(ps, 32);
                    ap[j] = ps;
                }
                if (lane == 0) {
                    #pragma unroll
                    for (int j = 0; j < 4; ++j) sden[par][j * 4 + wv] = ap[j];
                }
                __syncthreads();  // parity-buffered sden: race-free (r2 argument)
                #pragma unroll
                for (int j = 0; j < 4; ++j) {
                    const int bl = h * 4 + j;
                    const float4 dd = *(const float4*)&sden[par][j * 4];
                    const float c = ee[j] * __builtin_amdgcn_rcpf(dd.x + dd.y + dd.z + dd.w);
                    sacc[bl].x += c * pr[j].x; sacc[bl].y += c * pr[j].y;
                    sacc[bl].z += c * pr[j].z; sacc[bl].w += c * pr[j].w;
                }
            }
        }
    }

    // s_part stored as f16 pairs: [pc][b][nd4] uint2
    #pragma unroll
    for (int j = 0; j < BC; ++j) {
        uint2 u = { packh2(sacc[j].x, sacc[j].y), packh2(sacc[j].z, sacc[j].w) };
        s_part[((size_t)pcswz * B_SZ + (b0 + j)) * 256 + t] = u;
    }
}

// s[b][nd] = sum_pc s_part[pc][b][nd] (f16 partials, fp32 accum); v = squash(s).
// Grid (B, 4): block covers nd4 range q*64..q*64+63 (=8 whole n's).
// Thread t: nd4 = q*64 + (t&63), chunk subset (t>>6) of 4 x 64 chunks.
__global__ __launch_bounds__(256) void reduce_squash(
    const uint2* __restrict__ s_part, float* __restrict__ dst)
{
    const int t  = threadIdx.x;
    const int b  = blockIdx.x;
    const int q  = blockIdx.y;
    const int l  = t & 63;
    const int sub = t >> 6;
    const int nd4 = q * 64 + l;

    float4 s = make_float4(0.f, 0.f, 0.f, 0.f);
    for (int i = 0; i < NPC / 4; ++i) {
        const int pcid = sub + 4 * i;
        const float4 v = unpackh4(s_part[((size_t)pcid * B_SZ + b) * 256 + nd4]);
        s.x += v.x; s.y += v.y; s.z += v.z; s.w += v.w;
    }
    __shared__ float4 red[3][64];
    if (sub > 0) red[sub - 1][l] = s;
    __syncthreads();
    if (t < 64) {
        #pragma unroll
        for (int wvi = 0; wvi < 3; ++wvi) {
            const float4 r = red[wvi][t];
            s.x += r.x; s.y += r.y; s.z += r.z; s.w += r.w;
        }
        float sq = dot4(s, s);
        sq += __shfl_xor(sq, 1);
        sq += __shfl_xor(sq, 2);
        sq += __shfl_xor(sq, 4);
        const float f = sq / ((1.0f + sq) * sqrtf(sq + 1e-7f));
        ((float4*)dst)[(size_t)b * 256 + nd4] =
            make_float4(f * s.x, f * s.y, f * s.z, f * s.w);
    }
}

extern "C" void kernel_launch(void* const* d_in, const int* in_sizes, int n_in,
                              void* d_out, int out_size, void* d_ws, size_t ws_size,
                              hipStream_t stream)
{
    const float* x = (const float*)d_in[0];   // (B,P,pD)
    const float* w = (const float*)d_in[1];   // (P,N,D,pD)
    float* out = (float*)d_out;               // (B,N,D)
    float* ws  = (float*)d_ws;

    float*    v_buf  = ws;                                   // 65,536 f (256 KiB)
    float*    b_log  = ws + 65536;                           // 16 MiB
    uint2*    s_part = (uint2*)(ws + 65536 + 4194304);       // 32 MiB (f16 pairs)
    unsigned* w2     = (unsigned*)(ws + 12648448);           // 64 MiB
    uint4*    x2     = (uint4*)(ws + 12648448 + 16777216);   // 4 MiB
    // total ws use ~116 MiB (<= r5's validated footprint)

    repack_w<<<dim3(32768), dim3(256), 0, stream>>>((const float4*)w, w2);
    repack_x<<<dim3(1024),  dim3(256), 0, stream>>>((const float4*)x, (uint4*)x2);

    dim3 fg(NPC, NBC), fb(256);
    dim3 rg(B_SZ, 4), rb(256);

    fused_pass<0><<<fg, fb, 0, stream>>>(x2, (const uint4*)w2, nullptr, nullptr, s_part);
    reduce_squash<<<rg, rb, 0, stream>>>(s_part, v_buf);
    fused_pass<1><<<fg, fb, 0, stream>>>(x2, (const uint4*)w2, v_buf, b_log, s_part);
    reduce_squash<<<rg, rb, 0, stream>>>(s_part, v_buf);
    fused_pass<2><<<fg, fb, 0, stream>>>(x2, (const uint4*)w2, v_buf, b_log, s_part);
    reduce_squash<<<rg, rb, 0, stream>>>(s_part, v_buf);
    fused_pass<2><<<fg, fb, 0, stream>>>(x2, (const uint4*)w2, v_buf, b_log, s_part);
    reduce_squash<<<rg, rb, 0, stream>>>(s_part, out);
}

// Round 7
// 640.414 us; speedup vs baseline: 2.1326x; 2.1326x over previous
//
#include <hip/hip_runtime.h>
#include <math.h>

// DigitCaps routing constants
#define B_SZ 64
#define P_SZ 2048
#define PD   16
#define N_SZ 32
#define D_SZ 32
#define ND   1024            // N_SZ * D_SZ
#define PC   8               // p per fused block
#define BC   8               // b per fused block
#define NPC  (P_SZ / PC)     // 256
#define NBC  (B_SZ / BC)     // 8  -> grid 2048 blocks
// r7: launch_bounds stays (256,4) — 128-VGPR budget, ~2x headroom over the
// ~64-70 true demand (r5 binary proof). Occupancy comes from NATURAL VGPR
// use + 16.1 KiB LDS -> 7-8 blocks/CU. Forcing 8 via the bound (r6) spilled.

typedef _Float16 half2_t __attribute__((ext_vector_type(2)));

__device__ __forceinline__ float dot2acc(unsigned a, unsigned b, float acc) {
#if __has_builtin(__builtin_amdgcn_fdot2)
    return __builtin_amdgcn_fdot2(__builtin_bit_cast(half2_t, a),
                                  __builtin_bit_cast(half2_t, b), acc, false);
#else
    const half2_t ha = __builtin_bit_cast(half2_t, a);
    const half2_t hb = __builtin_bit_cast(half2_t, b);
    return acc + (float)ha[0] * (float)hb[0] + (float)ha[1] * (float)hb[1];
#endif
}

__device__ __forceinline__ unsigned packh2(float a, float b) {
    half2_t h; h[0] = (_Float16)a; h[1] = (_Float16)b;
    return __builtin_bit_cast(unsigned, h);
}

__device__ __forceinline__ float4 unpackh4(uint2 u) {
    const half2_t lo = __builtin_bit_cast(half2_t, u.x);
    const half2_t hi = __builtin_bit_cast(half2_t, u.y);
    return make_float4((float)lo[0], (float)lo[1], (float)hi[0], (float)hi[1]);
}

__device__ __forceinline__ float dot4(const float4 a, const float4 b) {
    return a.x * b.x + a.y * b.y + a.z * b.z + a.w * b.w;
}

// w (P,ND,PD) fp32 -> w2 f16, chunked so fused thread t reads coalesced:
// uint4 W[k] at w2u4[(p*8+k)*256 + t] holds w[p][4t + (k>>1)][(k&1)*8 .. +7]
__global__ __launch_bounds__(256) void repack_w(const float4* __restrict__ w4,
                                                unsigned* __restrict__ w2) {
    const size_t g = (size_t)blockIdx.x * 256 + threadIdx.x;  // < 8388608
    const float4 f4 = w4[g];
    const size_t f = g * 4;
    const int p  = (int)(f >> 14);
    const int nd = (int)((f >> 4) & 1023);
    const int q0 = (int)(f & 15);
    const int t  = nd >> 2, r = nd & 3;
    const int k  = r * 2 + (q0 >> 3);
    const int jp = (q0 & 7) >> 1;
    const size_t du = (((size_t)p * 8 + k) * 256 + t) * 4 + jp;
    uint2 val = { packh2(f4.x, f4.y), packh2(f4.z, f4.w) };
    *(uint2*)(w2 + du) = val;
}

// x (B,P,PD) fp32 -> x2 f16 pairs: x2u4[(b*P+p)*2 + half]
__global__ __launch_bounds__(256) void repack_x(const float4* __restrict__ x4,
                                                uint4* __restrict__ x2) {
    const size_t g = (size_t)blockIdx.x * 256 + threadIdx.x;  // < 262144
    const float4 a = x4[g * 2], b = x4[g * 2 + 1];
    uint4 o;
    o.x = packh2(a.x, a.y); o.y = packh2(a.z, a.w);
    o.z = packh2(b.x, b.y); o.w = packh2(b.z, b.w);
    x2[g] = o;
}

__device__ __forceinline__ float4 predict(const uint4 (&W)[8], const unsigned* X) {
    float s; float4 pr;
    s = dot2acc(W[0].x, X[0], 0.f); s = dot2acc(W[0].y, X[1], s);
    s = dot2acc(W[0].z, X[2], s);   s = dot2acc(W[0].w, X[3], s);
    s = dot2acc(W[1].x, X[4], s);   s = dot2acc(W[1].y, X[5], s);
    s = dot2acc(W[1].z, X[6], s);   s = dot2acc(W[1].w, X[7], s);
    pr.x = s;
    s = dot2acc(W[2].x, X[0], 0.f); s = dot2acc(W[2].y, X[1], s);
    s = dot2acc(W[2].z, X[2], s);   s = dot2acc(W[2].w, X[3], s);
    s = dot2acc(W[3].x, X[4], s);   s = dot2acc(W[3].y, X[5], s);
    s = dot2acc(W[3].z, X[6], s);   s = dot2acc(W[3].w, X[7], s);
    pr.y = s;
    s = dot2acc(W[4].x, X[0], 0.f); s = dot2acc(W[4].y, X[1], s);
    s = dot2acc(W[4].z, X[2], s);   s = dot2acc(W[4].w, X[3], s);
    s = dot2acc(W[5].x, X[4], s);   s = dot2acc(W[5].y, X[5], s);
    s = dot2acc(W[5].z, X[6], s);   s = dot2acc(W[5].w, X[7], s);
    pr.z = s;
    s = dot2acc(W[6].x, X[0], 0.f); s = dot2acc(W[6].y, X[1], s);
    s = dot2acc(W[6].z, X[2], s);   s = dot2acc(W[6].w, X[3], s);
    s = dot2acc(W[7].x, X[4], s);   s = dot2acc(W[7].y, X[5], s);
    s = dot2acc(W[7].z, X[6], s);   s = dot2acc(W[7].w, X[7], s);
    pr.w = s;
    return pr;
}

// One routing step. Thread t owns nd = 4t..4t+3 (n = t>>3).
// MODE==0: c=1/32; MODE==1: b=agr; MODE==2: b+=agr; c=softmax_n(b)
template <int MODE>
__global__ __launch_bounds__(256, 4) void fused_pass(
    const uint4* __restrict__ x2, const uint4* __restrict__ w2,
    const float* __restrict__ v_in, float* __restrict__ b_io,
    uint2* __restrict__ s_part)
{
    const int t     = threadIdx.x;
    const int pc    = blockIdx.x;
    const int pcswz = (pc & 7) * (NPC / 8) + (pc >> 3);
    const int bc    = blockIdx.y;          // 0..NBC-1
    const int p0    = pcswz * PC, b0 = bc * BC;
    const int n     = t >> 3;
    const int wv    = t >> 6;
    const int lane  = t & 63;

    __shared__ uint2 vs2[BC * 256];        // v as f16 pairs, 16 KiB
    __shared__ float sden[2][16];          // [epoch parity][j*4 + wave]

    if (MODE != 0) {
        const float4* vg = (const float4*)v_in;
        #pragma unroll
        for (int i = 0; i < BC; ++i) {
            const int idx = t + 256 * i;   // 0..2047
            const float4 vv = vg[(size_t)(b0 + (idx >> 8)) * 256 + (idx & 255)];
            uint2 u = { packh2(vv.x, vv.y), packh2(vv.z, vv.w) };
            vs2[idx] = u;
        }
        __syncthreads();
    }

    float4 sacc[BC];
    #pragma unroll
    for (int i = 0; i < BC; ++i) sacc[i] = make_float4(0.f, 0.f, 0.f, 0.f);

    const uint4* wbase = w2 + (size_t)p0 * (8 * 256) + t;
    const uint4* xbase = x2 + (size_t)b0 * P_SZ * 2;

    for (int pl = 0; pl < PC; ++pl) {
        const int p = p0 + pl;
        uint4 W[8];
        #pragma unroll
        for (int k = 0; k < 8; ++k) W[k] = wbase[(size_t)pl * 2048 + k * 256];

        if (MODE == 0) {
            #pragma unroll
            for (int j = 0; j < BC; ++j) {
                const uint4* xp = xbase + ((size_t)j * P_SZ + p) * 2;
                const uint4 xa = xp[0], xb = xp[1];
                const unsigned X[8] = {xa.x, xa.y, xa.z, xa.w, xb.x, xb.y, xb.z, xb.w};
                const float4 pr = predict(W, X);
                sacc[j].x += pr.x * (1.0f / 32.0f);
                sacc[j].y += pr.y * (1.0f / 32.0f);
                sacc[j].z += pr.z * (1.0f / 32.0f);
                sacc[j].w += pr.w * (1.0f / 32.0f);
            }
        } else {
            #pragma unroll
            for (int h = 0; h < 2; ++h) {
                const int par = h;
                float4 pr[4];
                float  ap[4], ee[4], bold[4];
                if (MODE == 2) {
                    #pragma unroll
                    for (int j = 0; j < 4; ++j)
                        bold[j] = b_io[((size_t)(b0 + h * 4 + j) * P_SZ + p) * N_SZ + n];
                }
                #pragma unroll
                for (int j = 0; j < 4; ++j) {
                    const int bl = h * 4 + j;
                    const uint4* xp = xbase + ((size_t)bl * P_SZ + p) * 2;
                    const uint4 xa = xp[0], xb = xp[1];
                    const unsigned X[8] = {xa.x, xa.y, xa.z, xa.w, xb.x, xb.y, xb.z, xb.w};
                    pr[j] = predict(W, X);
                    ap[j] = dot4(pr[j], unpackh4(vs2[bl * 256 + t]));
                }
                #pragma unroll
                for (int j = 0; j < 4; ++j) {
                    ap[j] += __shfl_xor(ap[j], 1);
                    ap[j] += __shfl_xor(ap[j], 2);
                    ap[j] += __shfl_xor(ap[j], 4);
                }
                #pragma unroll
                for (int j = 0; j < 4; ++j) {
                    const size_t bidx = ((size_t)(b0 + h * 4 + j) * P_SZ + p) * N_SZ + n;
                    const float bnew = (MODE == 1) ? ap[j] : (bold[j] + ap[j]);
                    if ((t & 7) == 0) b_io[bidx] = bnew;
                    ee[j] = __expf(bnew);
                }
                #pragma unroll
                for (int j = 0; j < 4; ++j) {
                    float ps = ee[j];
                    ps += __shfl_xor(ps, 8);
                    ps += __shfl_xor(ps, 16);
                    ps += __shfl_xor(ps, 32);
                    ap[j] = ps;
                }
                if (lane == 0) {
                    #pragma unroll
                    for (int j = 0; j < 4; ++j) sden[par][j * 4 + wv] = ap[j];
                }
                __syncthreads();  // parity-buffered sden: race-free (r2 argument)
                #pragma unroll
                for (int j = 0; j < 4; ++j) {
                    const int bl = h * 4 + j;
                    const float4 dd = *(const float4*)&sden[par][j * 4];
                    const float c = ee[j] * __builtin_amdgcn_rcpf(dd.x + dd.y + dd.z + dd.w);
                    sacc[bl].x += c * pr[j].x; sacc[bl].y += c * pr[j].y;
                    sacc[bl].z += c * pr[j].z; sacc[bl].w += c * pr[j].w;
                }
            }
        }
    }

    // s_part stored as f16 pairs (packs after sacc is dead — no live-range cost)
    #pragma unroll
    for (int j = 0; j < BC; ++j) {
        uint2 u = { packh2(sacc[j].x, sacc[j].y), packh2(sacc[j].z, sacc[j].w) };
        s_part[((size_t)pcswz * B_SZ + (b0 + j)) * 256 + t] = u;
    }
}

// s[b][nd] = sum_pc s_part[pc][b][nd] (f16 partials, fp32 accum); v = squash(s).
// Grid (B, 4): block covers nd4 range q*64..q*64+63. Thread t: nd4 = q*64+(t&63),
// chunk subset (t>>6).
__global__ __launch_bounds__(256) void reduce_squash(
    const uint2* __restrict__ s_part, float* __restrict__ dst)
{
    const int t  = threadIdx.x;
    const int b  = blockIdx.x;
    const int q  = blockIdx.y;
    const int l  = t & 63;
    const int sub = t >> 6;
    const int nd4 = q * 64 + l;

    float4 s = make_float4(0.f, 0.f, 0.f, 0.f);
    for (int i = 0; i < NPC / 4; ++i) {
        const int pcid = sub + 4 * i;
        const float4 v = unpackh4(s_part[((size_t)pcid * B_SZ + b) * 256 + nd4]);
        s.x += v.x; s.y += v.y; s.z += v.z; s.w += v.w;
    }
    __shared__ float4 red[3][64];
    if (sub > 0) red[sub - 1][l] = s;
    __syncthreads();
    if (t < 64) {
        #pragma unroll
        for (int wvi = 0; wvi < 3; ++wvi) {
            const float4 r = red[wvi][t];
            s.x += r.x; s.y += r.y; s.z += r.z; s.w += r.w;
        }
        float sq = dot4(s, s);
        sq += __shfl_xor(sq, 1);
        sq += __shfl_xor(sq, 2);
        sq += __shfl_xor(sq, 4);
        const float f = sq / ((1.0f + sq) * sqrtf(sq + 1e-7f));
        ((float4*)dst)[(size_t)b * 256 + nd4] =
            make_float4(f * s.x, f * s.y, f * s.z, f * s.w);
    }
}

extern "C" void kernel_launch(void* const* d_in, const int* in_sizes, int n_in,
                              void* d_out, int out_size, void* d_ws, size_t ws_size,
                              hipStream_t stream)
{
    const float* x = (const float*)d_in[0];   // (B,P,pD)
    const float* w = (const float*)d_in[1];   // (P,N,D,pD)
    float* out = (float*)d_out;               // (B,N,D)
    float* ws  = (float*)d_ws;

    float*    v_buf  = ws;                                   // 256 KiB
    float*    b_log  = ws + 65536;                           // 16 MiB
    uint2*    s_part = (uint2*)(ws + 65536 + 4194304);       // 32 MiB (f16 pairs)
    unsigned* w2     = (unsigned*)(ws + 12648448);           // 64 MiB
    uint4*    x2     = (uint4*)(ws + 12648448 + 16777216);   // 4 MiB

    repack_w<<<dim3(32768), dim3(256), 0, stream>>>((const float4*)w, w2);
    repack_x<<<dim3(1024),  dim3(256), 0, stream>>>((const float4*)x, (uint4*)x2);

    dim3 fg(NPC, NBC), fb(256);
    dim3 rg(B_SZ, 4), rb(256);

    fused_pass<0><<<fg, fb, 0, stream>>>(x2, (const uint4*)w2, nullptr, nullptr, s_part);
    reduce_squash<<<rg, rb, 0, stream>>>(s_part, v_buf);
    fused_pass<1><<<fg, fb, 0, stream>>>(x2, (const uint4*)w2, v_buf, b_log, s_part);
    reduce_squash<<<rg, rb, 0, stream>>>(s_part, v_buf);
    fused_pass<2><<<fg, fb, 0, stream>>>(x2, (const uint4*)w2, v_buf, b_log, s_part);
    reduce_squash<<<rg, rb, 0, stream>>>(s_part, v_buf);
    fused_pass<2><<<fg, fb, 0, stream>>>(x2, (const uint4*)w2, v_buf, b_log, s_part);
    reduce_squash<<<rg, rb, 0, stream>>>(s_part, out);
}

// Round 9
// 604.216 us; speedup vs baseline: 2.2603x; 1.0599x over previous
//
#include <hip/hip_runtime.h>
#include <math.h>

// DigitCaps routing constants
#define B_SZ 64
#define P_SZ 2048
#define PD   16
#define N_SZ 32
#define D_SZ 32
#define ND   1024            // N_SZ * D_SZ
#define PC   8               // p per fused block
#define BC   8               // b per fused block
#define NPC  (P_SZ / PC)     // 256
#define NBC  (B_SZ / BC)     // 8

typedef _Float16 half2_t __attribute__((ext_vector_type(2)));

__device__ __forceinline__ float dot2acc(unsigned a, unsigned b, float acc) {
#if __has_builtin(__builtin_amdgcn_fdot2)
    return __builtin_amdgcn_fdot2(__builtin_bit_cast(half2_t, a),
                                  __builtin_bit_cast(half2_t, b), acc, false);
#else
    const half2_t ha = __builtin_bit_cast(half2_t, a);
    const half2_t hb = __builtin_bit_cast(half2_t, b);
    return acc + (float)ha[0] * (float)hb[0] + (float)ha[1] * (float)hb[1];
#endif
}

__device__ __forceinline__ unsigned packh2(float a, float b) {
    half2_t h; h[0] = (_Float16)a; h[1] = (_Float16)b;
    return __builtin_bit_cast(unsigned, h);
}

__device__ __forceinline__ float4 unpackh4(uint2 u) {
    const half2_t lo = __builtin_bit_cast(half2_t, u.x);
    const half2_t hi = __builtin_bit_cast(half2_t, u.y);
    return make_float4((float)lo[0], (float)lo[1], (float)hi[0], (float)hi[1]);
}

__device__ __forceinline__ float dot4(const float4 a, const float4 b) {
    return a.x * b.x + a.y * b.y + a.z * b.z + a.w * b.w;
}

// w (P,ND,PD) fp32 -> w2 f16, chunked so fused thread t reads coalesced:
// uint4 W[k] at w2u4[(p*8+k)*256 + t] holds w[p][4t + (k>>1)][(k&1)*8 .. +7]
__global__ __launch_bounds__(256) void repack_w(const float4* __restrict__ w4,
                                                unsigned* __restrict__ w2) {
    const size_t g = (size_t)blockIdx.x * 256 + threadIdx.x;  // < 8388608
    const float4 f4 = w4[g];
    const size_t f = g * 4;
    const int p  = (int)(f >> 14);
    const int nd = (int)((f >> 4) & 1023);
    const int q0 = (int)(f & 15);
    const int t  = nd >> 2, r = nd & 3;
    const int k  = r * 2 + (q0 >> 3);
    const int jp = (q0 & 7) >> 1;
    const size_t du = (((size_t)p * 8 + k) * 256 + t) * 4 + jp;
    uint2 val = { packh2(f4.x, f4.y), packh2(f4.z, f4.w) };
    *(uint2*)(w2 + du) = val;
}

// x (B,P,PD) fp32 -> x2 f16 pairs: x2u4[(b*P+p)*2 + half]
__global__ __launch_bounds__(256) void repack_x(const float4* __restrict__ x4,
                                                uint4* __restrict__ x2) {
    const size_t g = (size_t)blockIdx.x * 256 + threadIdx.x;  // < 262144
    const float4 a = x4[g * 2], b = x4[g * 2 + 1];
    uint4 o;
    o.x = packh2(a.x, a.y); o.y = packh2(a.z, a.w);
    o.z = packh2(b.x, b.y); o.w = packh2(b.z, b.w);
    x2[g] = o;
}

__device__ __forceinline__ float4 predict(const uint4 (&W)[8], const unsigned* X) {
    float s; float4 pr;
    s = dot2acc(W[0].x, X[0], 0.f); s = dot2acc(W[0].y, X[1], s);
    s = dot2acc(W[0].z, X[2], s);   s = dot2acc(W[0].w, X[3], s);
    s = dot2acc(W[1].x, X[4], s);   s = dot2acc(W[1].y, X[5], s);
    s = dot2acc(W[1].z, X[6], s);   s = dot2acc(W[1].w, X[7], s);
    pr.x = s;
    s = dot2acc(W[2].x, X[0], 0.f); s = dot2acc(W[2].y, X[1], s);
    s = dot2acc(W[2].z, X[2], s);   s = dot2acc(W[2].w, X[3], s);
    s = dot2acc(W[3].x, X[4], s);   s = dot2acc(W[3].y, X[5], s);
    s = dot2acc(W[3].z, X[6], s);   s = dot2acc(W[3].w, X[7], s);
    pr.y = s;
    s = dot2acc(W[4].x, X[0], 0.f); s = dot2acc(W[4].y, X[1], s);
    s = dot2acc(W[4].z, X[2], s);   s = dot2acc(W[4].w, X[3], s);
    s = dot2acc(W[5].x, X[4], s);   s = dot2acc(W[5].y, X[5], s);
    s = dot2acc(W[5].z, X[6], s);   s = dot2acc(W[5].w, X[7], s);
    pr.z = s;
    s = dot2acc(W[6].x, X[0], 0.f); s = dot2acc(W[6].y, X[1], s);
    s = dot2acc(W[6].z, X[2], s);   s = dot2acc(W[6].w, X[3], s);
    s = dot2acc(W[7].x, X[4], s);   s = dot2acc(W[7].y, X[5], s);
    s = dot2acc(W[7].z, X[6], s);   s = dot2acc(W[7].w, X[7], s);
    pr.w = s;
    return pr;
}

// r7 fused kernel + optional pred f16 store (STORE_PRED, used for pass0).
// Thread t owns nd = 4t..4t+3 (n = t>>3).
// MODE==0: c=1/32; MODE==1: b=agr; MODE==2: b+=agr; c=softmax_n(b)
template <int MODE, bool STORE_PRED>
__global__ __launch_bounds__(256, 4) void fused_pass(
    const uint4* __restrict__ x2, const uint4* __restrict__ w2,
    const float* __restrict__ v_in, float* __restrict__ b_io,
    uint2* __restrict__ s_part, uint2* __restrict__ pred_out)
{
    const int t     = threadIdx.x;
    const int pc    = blockIdx.x;
    const int pcswz = (pc & 7) * (NPC / 8) + (pc >> 3);
    const int bc    = blockIdx.y;
    const int p0    = pcswz * PC, b0 = bc * BC;
    const int n     = t >> 3;
    const int wv    = t >> 6;
    const int lane  = t & 63;

    __shared__ uint2 vs2[BC * 256];        // v as f16 pairs, 16 KiB
    __shared__ float sden[2][16];

    if (MODE != 0) {
        const float4* vg = (const float4*)v_in;
        #pragma unroll
        for (int i = 0; i < BC; ++i) {
            const int idx = t + 256 * i;
            const float4 vv = vg[(size_t)(b0 + (idx >> 8)) * 256 + (idx & 255)];
            uint2 u = { packh2(vv.x, vv.y), packh2(vv.z, vv.w) };
            vs2[idx] = u;
        }
        __syncthreads();
    }

    float4 sacc[BC];
    #pragma unroll
    for (int i = 0; i < BC; ++i) sacc[i] = make_float4(0.f, 0.f, 0.f, 0.f);

    const uint4* wbase = w2 + (size_t)p0 * (8 * 256) + t;
    const uint4* xbase = x2 + (size_t)b0 * P_SZ * 2;

    for (int pl = 0; pl < PC; ++pl) {
        const int p = p0 + pl;
        uint4 W[8];
        #pragma unroll
        for (int k = 0; k < 8; ++k) W[k] = wbase[(size_t)pl * 2048 + k * 256];

        if (MODE == 0) {
            #pragma unroll
            for (int j = 0; j < BC; ++j) {
                const uint4* xp = xbase + ((size_t)j * P_SZ + p) * 2;
                const uint4 xa = xp[0], xb = xp[1];
                const unsigned X[8] = {xa.x, xa.y, xa.z, xa.w, xb.x, xb.y, xb.z, xb.w};
                const float4 pr = predict(W, X);
                if (STORE_PRED) {
                    uint2 u = { packh2(pr.x, pr.y), packh2(pr.z, pr.w) };
                    pred_out[((size_t)(b0 + j) * P_SZ + p) * 256 + t] = u;
                }
                sacc[j].x += pr.x * (1.0f / 32.0f);
                sacc[j].y += pr.y * (1.0f / 32.0f);
                sacc[j].z += pr.z * (1.0f / 32.0f);
                sacc[j].w += pr.w * (1.0f / 32.0f);
            }
        } else {
            #pragma unroll
            for (int h = 0; h < 2; ++h) {
                const int par = h;
                float4 pr[4];
                float  ap[4], ee[4], bold[4];
                if (MODE == 2) {
                    #pragma unroll
                    for (int j = 0; j < 4; ++j)
                        bold[j] = b_io[((size_t)(b0 + h * 4 + j) * P_SZ + p) * N_SZ + n];
                }
                #pragma unroll
                for (int j = 0; j < 4; ++j) {
                    const int bl = h * 4 + j;
                    const uint4* xp = xbase + ((size_t)bl * P_SZ + p) * 2;
                    const uint4 xa = xp[0], xb = xp[1];
                    const unsigned X[8] = {xa.x, xa.y, xa.z, xa.w, xb.x, xb.y, xb.z, xb.w};
                    pr[j] = predict(W, X);
                    ap[j] = dot4(pr[j], unpackh4(vs2[bl * 256 + t]));
                }
                #pragma unroll
                for (int j = 0; j < 4; ++j) {
                    ap[j] += __shfl_xor(ap[j], 1);
                    ap[j] += __shfl_xor(ap[j], 2);
                    ap[j] += __shfl_xor(ap[j], 4);
                }
                #pragma unroll
                for (int j = 0; j < 4; ++j) {
                    const size_t bidx = ((size_t)(b0 + h * 4 + j) * P_SZ + p) * N_SZ + n;
                    const float bnew = (MODE == 1) ? ap[j] : (bold[j] + ap[j]);
                    if ((t & 7) == 0) b_io[bidx] = bnew;
                    ee[j] = __expf(bnew);
                }
                #pragma unroll
                for (int j = 0; j < 4; ++j) {
                    float ps = ee[j];
                    ps += __shfl_xor(ps, 8);
                    ps += __shfl_xor(ps, 16);
                    ps += __shfl_xor(ps, 32);
                    ap[j] = ps;
                }
                if (lane == 0) {
                    #pragma unroll
                    for (int j = 0; j < 4; ++j) sden[par][j * 4 + wv] = ap[j];
                }
                __syncthreads();  // parity-buffered sden: race-free (r2 argument)
                #pragma unroll
                for (int j = 0; j < 4; ++j) {
                    const int bl = h * 4 + j;
                    const float4 dd = *(const float4*)&sden[par][j * 4];
                    const float c = ee[j] * __builtin_amdgcn_rcpf(dd.x + dd.y + dd.z + dd.w);
                    sacc[bl].x += c * pr[j].x; sacc[bl].y += c * pr[j].y;
                    sacc[bl].z += c * pr[j].z; sacc[bl].w += c * pr[j].w;
                }
            }
        }
    }

    #pragma unroll
    for (int j = 0; j < BC; ++j) {
        uint2 u = { packh2(sacc[j].x, sacc[j].y), packh2(sacc[j].z, sacc[j].w) };
        s_part[((size_t)pcswz * B_SZ + (b0 + j)) * 256 + t] = u;
    }
}

// Routing pass reading materialized pred (f16): no W, no dot2 — pure stream.
template <int MODE>
__global__ __launch_bounds__(256, 4) void routing_pass(
    const uint2* __restrict__ pred, const float* __restrict__ v_in,
    float* __restrict__ b_io, uint2* __restrict__ s_part)
{
    const int t     = threadIdx.x;
    const int pc    = blockIdx.x;
    const int pcswz = (pc & 7) * (NPC / 8) + (pc >> 3);
    const int bc    = blockIdx.y;
    const int p0    = pcswz * PC, b0 = bc * BC;
    const int n     = t >> 3;
    const int wv    = t >> 6;
    const int lane  = t & 63;

    __shared__ uint2 vs2[BC * 256];
    __shared__ float sden[2][16];

    {
        const float4* vg = (const float4*)v_in;
        #pragma unroll
        for (int i = 0; i < BC; ++i) {
            const int idx = t + 256 * i;
            const float4 vv = vg[(size_t)(b0 + (idx >> 8)) * 256 + (idx & 255)];
            uint2 u = { packh2(vv.x, vv.y), packh2(vv.z, vv.w) };
            vs2[idx] = u;
        }
        __syncthreads();
    }

    float4 sacc[BC];
    #pragma unroll
    for (int i = 0; i < BC; ++i) sacc[i] = make_float4(0.f, 0.f, 0.f, 0.f);

    for (int pl = 0; pl < PC; ++pl) {
        const int p = p0 + pl;
        #pragma unroll
        for (int h = 0; h < 2; ++h) {
            const int par = h;
            uint2  pu[4];
            float4 pr[4];
            float  ap[4], ee[4], bold[4];
            #pragma unroll
            for (int j = 0; j < 4; ++j)
                pu[j] = pred[((size_t)(b0 + h * 4 + j) * P_SZ + p) * 256 + t];
            if (MODE == 2) {
                #pragma unroll
                for (int j = 0; j < 4; ++j)
                    bold[j] = b_io[((size_t)(b0 + h * 4 + j) * P_SZ + p) * N_SZ + n];
            }
            #pragma unroll
            for (int j = 0; j < 4; ++j) {
                pr[j] = unpackh4(pu[j]);
                ap[j] = dot4(pr[j], unpackh4(vs2[(h * 4 + j) * 256 + t]));
            }
            #pragma unroll
            for (int j = 0; j < 4; ++j) {
                ap[j] += __shfl_xor(ap[j], 1);
                ap[j] += __shfl_xor(ap[j], 2);
                ap[j] += __shfl_xor(ap[j], 4);
            }
            #pragma unroll
            for (int j = 0; j < 4; ++j) {
                const size_t bidx = ((size_t)(b0 + h * 4 + j) * P_SZ + p) * N_SZ + n;
                const float bnew = (MODE == 1) ? ap[j] : (bold[j] + ap[j]);
                if ((t & 7) == 0) b_io[bidx] = bnew;
                ee[j] = __expf(bnew);
            }
            #pragma unroll
            for (int j = 0; j < 4; ++j) {
                float ps = ee[j];
                ps += __shfl_xor(ps, 8);
                ps += __shfl_xor(ps, 16);
                ps += __shfl_xor(ps, 32);
                ap[j] = ps;
            }
            if (lane == 0) {
                #pragma unroll
                for (int j = 0; j < 4; ++j) sden[par][j * 4 + wv] = ap[j];
            }
            __syncthreads();  // parity-buffered sden: race-free
            #pragma unroll
            for (int j = 0; j < 4; ++j) {
                const int bl = h * 4 + j;
                const float4 dd = *(const float4*)&sden[par][j * 4];
                const float c = ee[j] * __builtin_amdgcn_rcpf(dd.x + dd.y + dd.z + dd.w);
                sacc[bl].x += c * pr[j].x; sacc[bl].y += c * pr[j].y;
                sacc[bl].z += c * pr[j].z; sacc[bl].w += c * pr[j].w;
            }
        }
    }

    #pragma unroll
    for (int j = 0; j < BC; ++j) {
        uint2 u = { packh2(sacc[j].x, sacc[j].y), packh2(sacc[j].z, sacc[j].w) };
        s_part[((size_t)pcswz * B_SZ + (b0 + j)) * 256 + t] = u;
    }
}

// s[b][nd] = sum_pc s_part[pc][b][nd] (f16 partials, fp32 accum); v = squash(s).
__global__ __launch_bounds__(256) void reduce_squash(
    const uint2* __restrict__ s_part, float* __restrict__ dst)
{
    const int t  = threadIdx.x;
    const int b  = blockIdx.x;
    const int q  = blockIdx.y;
    const int l  = t & 63;
    const int sub = t >> 6;
    const int nd4 = q * 64 + l;

    float4 s = make_float4(0.f, 0.f, 0.f, 0.f);
    for (int i = 0; i < NPC / 4; ++i) {
        const int pcid = sub + 4 * i;
        const float4 v = unpackh4(s_part[((size_t)pcid * B_SZ + b) * 256 + nd4]);
        s.x += v.x; s.y += v.y; s.z += v.z; s.w += v.w;
    }
    __shared__ float4 red[3][64];
    if (sub > 0) red[sub - 1][l] = s;
    __syncthreads();
    if (t < 64) {
        #pragma unroll
        for (int wvi = 0; wvi < 3; ++wvi) {
            const float4 r = red[wvi][t];
            s.x += r.x; s.y += r.y; s.z += r.z; s.w += r.w;
        }
        float sq = dot4(s, s);
        sq += __shfl_xor(sq, 1);
        sq += __shfl_xor(sq, 2);
        sq += __shfl_xor(sq, 4);
        const float f = sq / ((1.0f + sq) * sqrtf(sq + 1e-7f));
        ((float4*)dst)[(size_t)b * 256 + nd4] =
            make_float4(f * s.x, f * s.y, f * s.z, f * s.w);
    }
}

extern "C" void kernel_launch(void* const* d_in, const int* in_sizes, int n_in,
                              void* d_out, int out_size, void* d_ws, size_t ws_size,
                              hipStream_t stream)
{
    const float* x = (const float*)d_in[0];   // (B,P,pD)
    const float* w = (const float*)d_in[1];   // (P,N,D,pD)
    float* out = (float*)d_out;               // (B,N,D)
    float* ws  = (float*)d_ws;

    // ---- workspace layout (float offsets), r9: NO overlaps except the
    // intentional b_log<->w2 alias in the pred path (w2 dead after pass0,
    // b_log first written in pass1).
    //   v_buf : [0,        65536)      256 KiB
    //   s_part: [65536,    8454144)    32 MiB  (4,194,304 uint2)
    //   w2    : [8454144,  25231360)   64 MiB  (16,777,216 u32)
    //   x2    : [25231360, 26279936)    4 MiB
    //   pred  : [26279936, 93388800)  256 MiB  (33,554,432 uint2)
    float*    v_buf  = ws;
    uint2*    s_part = (uint2*)(ws + 65536);
    unsigned* w2     = (unsigned*)(ws + 8454144);
    uint4*    x2     = (uint4*)(ws + 25231360);
    uint2*    pred   = (uint2*)(ws + 26279936);
    float*    b_pred = ws + 8454144;              // aliases w2 (safe: see above)
    float*    b_fb   = ws + 26279936;             // fallback: disjoint (pred unused)
    const size_t need = 93388800ull * 4ull;       // 373,555,200 B

    repack_w<<<dim3(32768), dim3(256), 0, stream>>>((const float4*)w, w2);
    repack_x<<<dim3(1024),  dim3(256), 0, stream>>>((const float4*)x, (uint4*)x2);

    dim3 fg(NPC, NBC), fb(256);
    dim3 rg(B_SZ, 4), rb(256);

    if (ws_size >= need) {
        // pass0 computes pred once + stores f16; passes 1-3 stream pred
        fused_pass<0, true><<<fg, fb, 0, stream>>>(x2, (const uint4*)w2, nullptr,
                                                   nullptr, s_part, pred);
        reduce_squash<<<rg, rb, 0, stream>>>(s_part, v_buf);
        routing_pass<1><<<fg, fb, 0, stream>>>(pred, v_buf, b_pred, s_part);
        reduce_squash<<<rg, rb, 0, stream>>>(s_part, v_buf);
        routing_pass<2><<<fg, fb, 0, stream>>>(pred, v_buf, b_pred, s_part);
        reduce_squash<<<rg, rb, 0, stream>>>(s_part, v_buf);
        routing_pass<2><<<fg, fb, 0, stream>>>(pred, v_buf, b_pred, s_part);
        reduce_squash<<<rg, rb, 0, stream>>>(s_part, out);
    } else {
        // r7 fallback (recompute pred every pass)
        fused_pass<0, false><<<fg, fb, 0, stream>>>(x2, (const uint4*)w2, nullptr,
                                                    nullptr, s_part, nullptr);
        reduce_squash<<<rg, rb, 0, stream>>>(s_part, v_buf);
        fused_pass<1, false><<<fg, fb, 0, stream>>>(x2, (const uint4*)w2, v_buf,
                                                    b_fb, s_part, nullptr);
        reduce_squash<<<rg, rb, 0, stream>>>(s_part, v_buf);
        fused_pass<2, false><<<fg, fb, 0, stream>>>(x2, (const uint4*)w2, v_buf,
                                                    b_fb, s_part, nullptr);
        reduce_squash<<<rg, rb, 0, stream>>>(s_part, v_buf);
        fused_pass<2, false><<<fg, fb, 0, stream>>>(x2, (const uint4*)w2, v_buf,
                                                    b_fb, s_part, nullptr);
        reduce_squash<<<rg, rb, 0, stream>>>(s_part, out);
    }
}